// Round 13
// baseline (172.119 us; speedup 1.0000x reference)
//
#include <hip/hip_runtime.h>
#include <hip/hip_bf16.h>
#include <math.h>

// Problem constants (fixed shapes from the reference)
constexpr int B_  = 4;
constexpr int N_  = 10000;
constexpr int E_  = 160000;
constexpr int D_  = 128;
constexpr int H_  = 4;
constexpr int O_  = 64;
constexpr float NEG_SLOPE = 0.2f;

using short8 = __attribute__((ext_vector_type(8))) short;
using f32x4  = __attribute__((ext_vector_type(4))) float;

static __device__ __forceinline__ unsigned short f2bf(float f) {
    unsigned u = __float_as_uint(f);
    u += 0x7fffu + ((u >> 16) & 1u);           // RN-even
    return (unsigned short)(u >> 16);
}
static __device__ __forceinline__ float bf2f(unsigned short h) {
    return __uint_as_float((unsigned)h << 16);
}

// ---------------------------------------------------------------------------
// k_prep, 128 blocks:
//   block d: W1t bf16 of Wsrc[d][h][o] -> [c][d], c = o*4+h (B-operand layout)
//            v_src[d][h], v_dst[d][h] row reductions.
//   all blocks: grid-stride zero of deg[]; block 0: c[h].
// ---------------------------------------------------------------------------
__global__ __launch_bounds__(256) void k_prep(
    const float* __restrict__ Wsrc, const float* __restrict__ att_src,
    const float* __restrict__ att_dst,
    const float* __restrict__ W_edge, const float* __restrict__ att_edge,
    unsigned short* __restrict__ W1t,
    float* __restrict__ vsrc, float* __restrict__ vdst,
    int* __restrict__ deg, float* __restrict__ c)
{
    const int d = blockIdx.x;
    const int t = threadIdx.x;
    const int h = t >> 6;

    for (int i = d * 256 + t; i < N_; i += 128 * 256) deg[i] = 0;

    const float wv = Wsrc[(size_t)d * 256 + t];
    const int cc = ((t & 63) << 2) | h;      // o*4 + head
    W1t[(size_t)cc * 128 + d] = f2bf(wv);

    float vs = wv * att_src[t];
    float vd = wv * att_dst[t];
#pragma unroll
    for (int off = 32; off > 0; off >>= 1) {
        vs += __shfl_down(vs, off, 64);
        vd += __shfl_down(vd, off, 64);
    }
    if ((t & 63) == 0) {
        vsrc[d * 4 + h] = vs;
        vdst[d * 4 + h] = vd;
    }

    if (d == 0) {
        float v = W_edge[t] * att_edge[t];
#pragma unroll
        for (int off = 32; off > 0; off >>= 1) v += __shfl_down(v, off, 64);
        if ((t & 63) == 0) c[h] = v;
    }
}

// ---------------------------------------------------------------------------
// k_gemm (MFMA). R13: (a) x-staging with explicit 4-deep load ILP,
// (b) epilogue-2 pair-packs bf16 cols via shfl_xor(1) -> 16 ds_write_b32
//     per thread instead of 32 scalar ds_write_u16 (R11 counter: 4.88M LDS
//     conflict cycles ~16% of kernel time).
// ---------------------------------------------------------------------------
__global__ __launch_bounds__(256) void k_gemm(
    const float* __restrict__ x, const int* __restrict__ ei,
    const unsigned short* __restrict__ W1t,
    const float* __restrict__ vsrc, const float* __restrict__ vdst,
    unsigned short* __restrict__ hbw, float* __restrict__ asrc, float* __restrict__ adst,
    int* __restrict__ deg, int* __restrict__ rank)
{
    constexpr int ROWS = 32;
    constexpr int APAD = 136;                // ushort stride (128+8), 272B = 16B-mult
    __shared__ uint4 SHq[1024];              // 16384 B: A1 (8704) then Cb (16384)
    __shared__ float4 vsL[128];
    __shared__ float4 vdL[128];
    unsigned short* A1 = (unsigned short*)SHq;
    unsigned short* Cb = (unsigned short*)SHq;

    const int t = threadIdx.x;
    const int w = t >> 6;
    const int lane = t & 63;
    const int i = lane & 15;
    const int q = lane >> 4;
    const size_t rowbase = (size_t)blockIdx.x * ROWS;

    // ---- prefetch all B fragments into registers (16 independent loads) ----
    short8 breg[4][4];                       // [ks][ctl]
#pragma unroll
    for (int ks = 0; ks < 4; ++ks)
#pragma unroll
        for (int ctl = 0; ctl < 4; ++ctl) {
            const size_t boff = (size_t)((w * 4 + ctl) * 16 + i) * 128 + ks * 32 + q * 8;
            breg[ks][ctl] = *(const short8*)&W1t[boff];
        }

    // ---- stage x -> bf16 in LDS: all 4 loads issued before any convert ----
    {
        const float4* xg = (const float4*)(x + rowbase * D_);
        float4 xv[4];
#pragma unroll
        for (int it = 0; it < 4; ++it) xv[it] = xg[it * 256 + t];
        if (t < 128) vsL[t] = ((const float4*)vsrc)[t];
        else         vdL[t - 128] = ((const float4*)vdst)[t - 128];
#pragma unroll
        for (int it = 0; it < 4; ++it) {
            const int idx = it * 256 + t;    // 1024 float4 = 32 rows x 32
            const int row = idx >> 5;
            const int c4  = idx & 31;
            ushort4 h1;
            h1.x = f2bf(xv[it].x); h1.y = f2bf(xv[it].y);
            h1.z = f2bf(xv[it].z); h1.w = f2bf(xv[it].w);
            *(ushort4*)&A1[row * APAD + c4 * 4] = h1;
        }
    }
    __syncthreads();

    // ---- MFMA main loop: pure ds_read + MFMA (B already in registers) ----
    f32x4 acc[2][4];
#pragma unroll
    for (int tl = 0; tl < 2; ++tl)
#pragma unroll
        for (int ctl = 0; ctl < 4; ++ctl) acc[tl][ctl] = (f32x4){0.f, 0.f, 0.f, 0.f};

#pragma unroll
    for (int ks = 0; ks < 4; ++ks) {
        const int a0off = i * APAD + ks * 32 + q * 8;
        const int a1off = (16 + i) * APAD + ks * 32 + q * 8;
        short8 at0 = *(const short8*)&A1[a0off];
        short8 at1 = *(const short8*)&A1[a1off];
#pragma unroll
        for (int ctl = 0; ctl < 4; ++ctl) {
            acc[0][ctl] = __builtin_amdgcn_mfma_f32_16x16x32_bf16(at0, breg[ks][ctl], acc[0][ctl], 0, 0, 0);
            acc[1][ctl] = __builtin_amdgcn_mfma_f32_16x16x32_bf16(at1, breg[ks][ctl], acc[1][ctl], 0, 0, 0);
        }
    }

    {   // epilogue 1: a_src/a_dst from bf16(x) . v
        const int r = lane >> 3, g = lane & 7;
        const int row_l = w * 8 + r;
        float s0 = 0, s1 = 0, s2 = 0, s3 = 0, d0 = 0, d1 = 0, d2 = 0, d3 = 0;
#pragma unroll
        for (int dd4 = 0; dd4 < 4; ++dd4) {
            const int db = g * 16 + dd4 * 4;
            ushort4 u1 = *(const ushort4*)&A1[row_l * APAD + db];
            const float xv0 = bf2f(u1.x);
            const float xv1 = bf2f(u1.y);
            const float xv2 = bf2f(u1.z);
            const float xv3 = bf2f(u1.w);
            float4 vsa = vsL[db + 0], vda = vdL[db + 0];
            float4 vsb = vsL[db + 1], vdb = vdL[db + 1];
            float4 vsc = vsL[db + 2], vdc = vdL[db + 2];
            float4 vsd = vsL[db + 3], vdd = vdL[db + 3];
            s0 = fmaf(xv0, vsa.x, s0); s1 = fmaf(xv0, vsa.y, s1);
            s2 = fmaf(xv0, vsa.z, s2); s3 = fmaf(xv0, vsa.w, s3);
            d0 = fmaf(xv0, vda.x, d0); d1 = fmaf(xv0, vda.y, d1);
            d2 = fmaf(xv0, vda.z, d2); d3 = fmaf(xv0, vda.w, d3);
            s0 = fmaf(xv1, vsb.x, s0); s1 = fmaf(xv1, vsb.y, s1);
            s2 = fmaf(xv1, vsb.z, s2); s3 = fmaf(xv1, vsb.w, s3);
            d0 = fmaf(xv1, vdb.x, d0); d1 = fmaf(xv1, vdb.y, d1);
            d2 = fmaf(xv1, vdb.z, d2); d3 = fmaf(xv1, vdb.w, d3);
            s0 = fmaf(xv2, vsc.x, s0); s1 = fmaf(xv2, vsc.y, s1);
            s2 = fmaf(xv2, vsc.z, s2); s3 = fmaf(xv2, vsc.w, s3);
            d0 = fmaf(xv2, vdc.x, d0); d1 = fmaf(xv2, vdc.y, d1);
            d2 = fmaf(xv2, vdc.z, d2); d3 = fmaf(xv2, vdc.w, d3);
            s0 = fmaf(xv3, vsd.x, s0); s1 = fmaf(xv3, vsd.y, s1);
            s2 = fmaf(xv3, vsd.z, s2); s3 = fmaf(xv3, vsd.w, s3);
            d0 = fmaf(xv3, vdd.x, d0); d1 = fmaf(xv3, vdd.y, d1);
            d2 = fmaf(xv3, vdd.z, d2); d3 = fmaf(xv3, vdd.w, d3);
        }
#pragma unroll
        for (int off = 4; off > 0; off >>= 1) {
            s0 += __shfl_down(s0, off, 64); s1 += __shfl_down(s1, off, 64);
            s2 += __shfl_down(s2, off, 64); s3 += __shfl_down(s3, off, 64);
            d0 += __shfl_down(d0, off, 64); d1 += __shfl_down(d1, off, 64);
            d2 += __shfl_down(d2, off, 64); d3 += __shfl_down(d3, off, 64);
        }
        if (g == 0) {
            const size_t rg = rowbase + row_l;
            *(float4*)&asrc[rg * 4] = make_float4(s0, s1, s2, s3);
            *(float4*)&adst[rg * 4] = make_float4(d0, d1, d2, d3);
        }
    }

    // ---- epilogue 2: pair-packed C via XOR-swizzled LDS, full-line stores ----
    __syncthreads();                         // A1 dead; reuse as Cb
    {
        const bool odd = (i & 1);
#pragma unroll
        for (int ctl = 0; ctl < 4; ++ctl) {
            const int col  = (w * 4 + ctl) * 16 + i;
            const int colp = col & ~1;
            const int chnk = colp >> 3;
            const int wd   = (colp & 7) >> 1;
#pragma unroll
            for (int r = 0; r < 4; ++r) {
                unsigned u0 = f2bf(acc[0][ctl][r]);
                unsigned u1 = f2bf(acc[1][ctl][r]);
                unsigned p0 = (unsigned)__shfl_xor((int)u0, 1, 64);
                unsigned p1 = (unsigned)__shfl_xor((int)u1, 1, 64);
                // even lane writes tl=0 pair, odd lane writes tl=1 pair
                unsigned packed = odd ? ((p1 & 0xffffu) | (u1 << 16))
                                      : ((u0 & 0xffffu) | (p0 << 16));
                const int tl  = odd ? 1 : 0;
                const int row = tl * 16 + q * 4 + r;
                const int s   = chnk ^ row;
                ((unsigned*)Cb)[row * 128 + s * 4 + wd] = packed;
            }
        }
    }
    __syncthreads();
    {
        const int chnk = t & 31;
#pragma unroll
        for (int k = 0; k < 4; ++k) {
            const int row = k * 8 + (t >> 5);
            const int s = chnk ^ row;
            const uint4 v = *(const uint4*)&Cb[row * 256 + s * 8];
            *(uint4*)&hbw[(rowbase + row) * 256 + chnk * 8] = v;
        }
    }

    // ---- fused histogram + rank at kernel END (no barrier after) ----
    if (t < 128) {
        const int ee = blockIdx.x * 128 + t;
        rank[ee] = atomicAdd(&deg[ei[E_ + ee]], 1);
    }
}

// ---------------------------------------------------------------------------
// k_scan: single-block exclusive prefix sum, 2 barriers total.
// ---------------------------------------------------------------------------
__global__ __launch_bounds__(1024) void k_scan(const int* __restrict__ deg,
                                               int* __restrict__ rowptr)
{
    __shared__ int wsum[16], wexcl[16];
    const int t = threadIdx.x, wv = t >> 6, ln = t & 63;
    const int base = t * 10;
    int v[10];
    int tot = 0;
    if (base < N_) {
#pragma unroll
        for (int i = 0; i < 10; ++i) { v[i] = deg[base + i]; tot += v[i]; }
    }
    int incl = tot;
#pragma unroll
    for (int off = 1; off < 64; off <<= 1) {
        int u = __shfl_up(incl, off, 64);
        if (ln >= off) incl += u;
    }
    if (ln == 63) wsum[wv] = incl;
    __syncthreads();
    if (wv == 0 && ln < 16) {
        int s = wsum[ln];
        int si = s;
#pragma unroll
        for (int off = 1; off < 16; off <<= 1) {
            int u = __shfl_up(si, off, 64);
            if (ln >= off) si += u;
        }
        wexcl[ln] = si - s;
    }
    __syncthreads();
    if (base < N_) {
        int run = wexcl[wv] + incl - tot;
#pragma unroll
        for (int i = 0; i < 10; ++i) {
            rowptr[base + i] = run; run += v[i];
        }
    }
    if (t == 0) rowptr[N_] = E_;
}

// ---------------------------------------------------------------------------
// k_place: atomic-free counting-sort placement using precomputed rank.
// ---------------------------------------------------------------------------
__global__ __launch_bounds__(256) void k_place(
    const int* __restrict__ ei, const float* __restrict__ eattr,
    const int* __restrict__ rowptr, const int* __restrict__ rank,
    int2* __restrict__ srcea)
{
    const int e = blockIdx.x * 256 + threadIdx.x;
    if (e >= E_) return;
    const int dst = ei[E_ + e];
    const int pos = rowptr[dst] + rank[e];
    srcea[pos] = make_int2(ei[e], __float_as_int(eattr[e]));
}

// ---------------------------------------------------------------------------
// k_agg: one wave per (dst,b), b = blockIdx&3 (XCD<->batch affinity; R9
// lesson). R13: FORCED 8-deep gather MLP — R10's VGPR_Count=24 proved the
// compiler serialized the "unroll-4" loads into a 1-deep chain; explicit
// arrays (all 8 loads before any use) + zero-padded chunks (p=0 for invalid
// slots -> no serialized scalar tail) make the gather pipeline real.
// ---------------------------------------------------------------------------
__global__ __launch_bounds__(256) void k_agg(
    const int* __restrict__ rowptr, const int2* __restrict__ srcea,
    const float* __restrict__ asrc, const float* __restrict__ adst,
    const float* __restrict__ cvec, const unsigned short* __restrict__ hbu,
    const float* __restrict__ bias, float* __restrict__ out)
{
    __shared__ float pS[4][64][4];       // [wave][j][h]  4 KB
    __shared__ int   baseS[4][64];       // hb row start (ushort idx)  1 KB

    const int b    = blockIdx.x & 3;
    const int g    = blockIdx.x >> 2;
    const int wave = threadIdx.x >> 6;
    const int lane = threadIdx.x & 63;
    const int dst  = g * 4 + wave;

    const int start = rowptr[dst];
    const int end   = rowptr[dst + 1];

    const float4 ad = *(const float4*)&adst[((size_t)b * N_ + dst) * 4];
    const float4 cc = *(const float4*)cvec;

    float a0[4] = {0.f, 0.f, 0.f, 0.f};
    float a1[4] = {0.f, 0.f, 0.f, 0.f};
    float a2[4] = {0.f, 0.f, 0.f, 0.f};
    float a3[4] = {0.f, 0.f, 0.f, 0.f};
    float q0 = 0.f, q1 = 0.f, q2 = 0.f, q3 = 0.f;

    for (int c0 = start; c0 < end; c0 += 64) {
        const int jl = c0 + lane;
        const bool valid = jl < end;
        const int2 rec = srcea[valid ? jl : start];
        const int   srcl = rec.x;
        const float ea   = __int_as_float(rec.y);
        const float4 as = *(const float4*)&asrc[((size_t)b * N_ + srcl) * 4];
        float4 al;
        al.x = as.x + ad.x + ea * cc.x;
        al.y = as.y + ad.y + ea * cc.y;
        al.z = as.z + ad.z + ea * cc.z;
        al.w = as.w + ad.w + ea * cc.w;
        al.x = al.x > 0.f ? al.x : NEG_SLOPE * al.x;
        al.y = al.y > 0.f ? al.y : NEG_SLOPE * al.y;
        al.z = al.z > 0.f ? al.z : NEG_SLOPE * al.z;
        al.w = al.w > 0.f ? al.w : NEG_SLOPE * al.w;
        const float px = valid ? __expf(al.x) : 0.f;
        const float py = valid ? __expf(al.y) : 0.f;
        const float pz = valid ? __expf(al.z) : 0.f;
        const float pw = valid ? __expf(al.w) : 0.f;
        q0 += px; q1 += py; q2 += pz; q3 += pw;

        *(float4*)&pS[wave][lane][0] = make_float4(px, py, pz, pw);
        baseS[wave][lane] = (b * N_ + srcl) << 8;        // row base (ushorts)
        __builtin_amdgcn_wave_barrier();

        const int cnt = min(64, end - c0);
        const int lo4 = lane * 4;
        // full 8-wide iterations: slots >= cnt carry p=0 and a safe base
        for (int j = 0; j < cnt; j += 8) {
            float4  pv[8];
            int     rr[8];
            ushort4 hv[8];
#pragma unroll
            for (int k = 0; k < 8; ++k) pv[k] = *(const float4*)&pS[wave][j + k][0];
#pragma unroll
            for (int k = 0; k < 8; ++k) rr[k] = baseS[wave][j + k];
#pragma unroll
            for (int k = 0; k < 8; ++k) hv[k] = *(const ushort4*)&hbu[(size_t)rr[k] + lo4];
#pragma unroll
            for (int k = 0; k < 8; ++k) {
                float* A = (k & 2) ? ((k & 1) ? a3 : a2) : ((k & 1) ? a1 : a0);
                A[0] = fmaf(pv[k].x, bf2f(hv[k].x), A[0]);
                A[1] = fmaf(pv[k].y, bf2f(hv[k].y), A[1]);
                A[2] = fmaf(pv[k].z, bf2f(hv[k].z), A[2]);
                A[3] = fmaf(pv[k].w, bf2f(hv[k].w), A[3]);
            }
        }
        __builtin_amdgcn_wave_barrier();
    }

    // denominator: butterfly reduce-all over lanes
#pragma unroll
    for (int off = 32; off > 0; off >>= 1) {
        q0 += __shfl_xor(q0, off, 64);
        q1 += __shfl_xor(q1, off, 64);
        q2 += __shfl_xor(q2, off, 64);
        q3 += __shfl_xor(q3, off, 64);
    }

    const float r = (a0[0] + a1[0] + a2[0] + a3[0]) / fmaxf(q0, 1e-16f)
                  + (a0[1] + a1[1] + a2[1] + a3[1]) / fmaxf(q1, 1e-16f)
                  + (a0[2] + a1[2] + a2[2] + a3[2]) / fmaxf(q2, 1e-16f)
                  + (a0[3] + a1[3] + a2[3] + a3[3]) / fmaxf(q3, 1e-16f);
    out[((size_t)b * N_ + dst) * O_ + lane] = 0.25f * r + bias[lane];
}

// ---------------------------------------------------------------------------
extern "C" void kernel_launch(void* const* d_in, const int* in_sizes, int n_in,
                              void* d_out, int out_size, void* d_ws, size_t ws_size,
                              hipStream_t stream)
{
    (void)in_sizes; (void)n_in; (void)out_size; (void)ws_size;
    const float* x        = (const float*)d_in[0];
    const int*   ei       = (const int*)d_in[1];     // int64 in ref -> int32 here
    const float* eattr    = (const float*)d_in[2];
    const float* Wsrc     = (const float*)d_in[3];
    const float* att_src  = (const float*)d_in[4];
    const float* att_dst  = (const float*)d_in[5];
    const float* W_edge   = (const float*)d_in[6];
    const float* att_edge = (const float*)d_in[7];
    const float* bias     = (const float*)d_in[8];
    float* out = (float*)d_out;

    // workspace carve-up (16B-aligned chunks)
    char* w = (char*)d_ws;
    auto take = [&](size_t bytes) { char* p = w; w += (bytes + 15) & ~size_t(15); return p; };
    unsigned short* hb   = (unsigned short*)take((size_t)B_ * N_ * O_ * H_ * 2); // 20.48 MB
    float* asrc    = (float*)take((size_t)B_ * N_ * H_ * 4);                     // 640 KB
    float* adst    = (float*)take((size_t)B_ * N_ * H_ * 4);
    float* c       = (float*)take(4 * 4);
    unsigned short* W1t = (unsigned short*)take((size_t)256 * 128 * 2);          // 64 KB
    float* vsrc    = (float*)take((size_t)128 * 4 * 4);                          // 2 KB
    float* vdst    = (float*)take((size_t)128 * 4 * 4);
    int* deg       = (int*)take((size_t)N_ * 4);
    int* rowptr    = (int*)take((size_t)(N_ + 1) * 4);
    int* rank      = (int*)take((size_t)E_ * 4);                                 // 640 KB
    int2* srcea    = (int2*)take((size_t)E_ * 8);                                // 1.28 MB

    hipLaunchKernelGGL(k_prep, dim3(128), dim3(256), 0, stream,
                       Wsrc, att_src, att_dst, W_edge, att_edge,
                       W1t, vsrc, vdst, deg, c);
    hipLaunchKernelGGL(k_gemm, dim3((B_ * N_) / 32), dim3(256), 0, stream,
                       x, ei, W1t, vsrc, vdst, hb, asrc, adst, deg, rank);
    hipLaunchKernelGGL(k_scan, dim3(1), dim3(1024), 0, stream, deg, rowptr);
    hipLaunchKernelGGL(k_place, dim3((E_ + 255) / 256), dim3(256), 0, stream,
                       ei, eattr, rowptr, rank, srcea);
    hipLaunchKernelGGL(k_agg, dim3(N_ / 4 * B_), dim3(256), 0, stream,
                       rowptr, srcea, asrc, adst, c, hb, bias, out);
}